// Round 9
// baseline (2356.471 us; speedup 1.0000x reference)
//
#include <hip/hip_runtime.h>
#include <cstdint>
#include <cstddef>

typedef __attribute__((ext_vector_type(8))) short short8;
typedef __attribute__((ext_vector_type(4))) float floatx4;
typedef unsigned short u16;
typedef unsigned long long u64;

#define NSTEP 256

__device__ __forceinline__ unsigned f2b_rne(float x) {
  unsigned u = __builtin_bit_cast(unsigned, x);
  return (u + 0x7fffu + ((u >> 16) & 1u)) >> 16;
}
__device__ __forceinline__ float b2f(u16 b) {
  unsigned u = ((unsigned)b) << 16;
  return __builtin_bit_cast(float, u);
}
__device__ __forceinline__ float sigf(float x) {
  x = fminf(fmaxf(x, -30.f), 30.f);
  return __builtin_amdgcn_rcpf(1.f + __expf(-x));
}
__device__ __forceinline__ float tanhf_fast(float x) {
  x = fminf(fmaxf(x, -15.f), 15.f);
  float e = __expf(2.f * x);
  return (e - 1.f) * __builtin_amdgcn_rcpf(e + 1.f);
}

// agent-scope relaxed atomics: execute at the coherence point, bypass L1/L2.
__device__ __forceinline__ unsigned ald(const unsigned* p) {
  return __hip_atomic_load(p, __ATOMIC_RELAXED, __HIP_MEMORY_SCOPE_AGENT);
}
__device__ __forceinline__ void ast(unsigned* p, unsigned v) {
  __hip_atomic_store(p, v, __ATOMIC_RELAXED, __HIP_MEMORY_SCOPE_AGENT);
}

// ---------------- init: zero h rows t=0 (u32 view) ----------------
__global__ void init_kernel(unsigned* h0, unsigned* h1) {
  int i = blockIdx.x * blockDim.x + threadIdx.x;
  if (i < 32768) { h0[i] = 0; h1[i] = 0; }
}

// ---------------- init2: zero flag region ----------------
__global__ void init2_kernel(unsigned* fl) {
  int i = blockIdx.x * blockDim.x + threadIdx.x;
  if (i < 2048) fl[i] = 0;
}

// ---------------- fp32 -> bf16 cast (vectorized x4) ----------------
__global__ void cast_kernel(const float* __restrict__ in, u16* __restrict__ out, int n4) {
  int i = blockIdx.x * blockDim.x + threadIdx.x;
  int stride = gridDim.x * blockDim.x;
  for (; i < n4; i += stride) {
    float4 v = ((const float4*)in)[i];
    unsigned lo = f2b_rne(v.x) | (f2b_rne(v.y) << 16);
    unsigned hi = f2b_rne(v.z) | (f2b_rne(v.w) << 16);
    ((uint2*)out)[i] = make_uint2(lo, hi);
  }
}

// per-wave K-quarter GEMM accumulate over one blocked h row.
// H layout (dwords per 32768-dword row): word(b,j) at (j>>4)*512 + b*8 + ((j&15)>>1).
// Round-8 proven scheduling: issue ALL 32 fragment loads, PIN with asm("+v")
// (grid-bound occupancy -> registers free), then run all 128 MFMAs. One
// pipelined MALL latency exposure instead of ~8 serialized round trips.
#define GEMM_Q(HROW, W)                                                        \
  {                                                                            \
    short8 a_[8][4];                                                           \
    _Pragma("unroll")                                                          \
    for (int c_ = 0; c_ < 8; ++c_) {                                           \
      int k_ = kq0 + c_ * 32 + q * 8;                                          \
      const unsigned* base_ = (HROW) + (k_ >> 4) * 512 + ((k_ & 15) >> 1);     \
      _Pragma("unroll")                                                        \
      for (int m_ = 0; m_ < 4; ++m_)                                           \
        a_[c_][m_] = *(const short8*)(base_ + (m_ * 16 + n16) * 8);            \
    }                                                                          \
    _Pragma("unroll")                                                          \
    for (int c_ = 0; c_ < 8; ++c_)                                             \
      _Pragma("unroll")                                                        \
      for (int m_ = 0; m_ < 4; ++m_)                                           \
        asm volatile("" : "+v"(a_[c_][m_]));                                   \
    _Pragma("unroll")                                                          \
    for (int c_ = 0; c_ < 8; ++c_)                                             \
      _Pragma("unroll")                                                        \
      for (int m_ = 0; m_ < 4; ++m_)                                           \
        _Pragma("unroll")                                                      \
        for (int g_ = 0; g_ < 4; ++g_)                                         \
          acc[m_][g_] = __builtin_amdgcn_mfma_f32_16x16x32_bf16(a_[c_][m_], (W)[g_][c_], acc[m_][g_], 0, 0, 0); \
  }

// same, but A is a row-major [64][1024] bf16 block (X rows; u16* base).
#define GEMM_QX(XROW, W)                                                       \
  {                                                                            \
    short8 a_[8][4];                                                           \
    _Pragma("unroll")                                                          \
    for (int c_ = 0; c_ < 8; ++c_) {                                           \
      int k_ = kq0 + c_ * 32 + q * 8;                                          \
      _Pragma("unroll")                                                        \
      for (int m_ = 0; m_ < 4; ++m_)                                           \
        a_[c_][m_] = *(const short8*)((XROW) + (size_t)(m_ * 16 + n16) * 1024 + k_); \
    }                                                                          \
    _Pragma("unroll")                                                          \
    for (int c_ = 0; c_ < 8; ++c_)                                             \
      _Pragma("unroll")                                                        \
      for (int m_ = 0; m_ < 4; ++m_)                                           \
        asm volatile("" : "+v"(a_[c_][m_]));                                   \
    _Pragma("unroll")                                                          \
    for (int c_ = 0; c_ < 8; ++c_)                                             \
      _Pragma("unroll")                                                        \
      for (int m_ = 0; m_ < 4; ++m_)                                           \
        _Pragma("unroll")                                                      \
        for (int g_ = 0; g_ < 4; ++g_)                                         \
          acc[m_][g_] = __builtin_amdgcn_mfma_f32_16x16x32_bf16(a_[c_][m_], (W)[g_][c_], acc[m_][g_], 0, 0, 0); \
  }

// cross-wave K reduction via LDS; after this, tot[g] = full-K sums for m=wv.
#define REDUCE_TOT()                                                           \
  _Pragma("unroll")                                                            \
  for (int m_ = 0; m_ < 4; ++m_) {                                             \
    if (m_ != wv) {                                                            \
      int slot_ = (m_ - (m_ > wv ? 1 : 0)) * 4;                                \
      _Pragma("unroll")                                                        \
      for (int g_ = 0; g_ < 4; ++g_)                                           \
        *(floatx4*)&red[wv][slot_ + g_][lane * 4] = acc[m_][g_];               \
    }                                                                          \
  }                                                                            \
  __syncthreads();                                                             \
  _Pragma("unroll")                                                            \
  for (int g_ = 0; g_ < 4; ++g_) tot[g_] = acc[wv][g_];                        \
  _Pragma("unroll")                                                            \
  for (int w2_ = 0; w2_ < 4; ++w2_) {                                          \
    if (w2_ != wv) {                                                           \
      int slot_ = (wv - (wv > w2_ ? 1 : 0)) * 4;                               \
      _Pragma("unroll")                                                        \
      for (int g_ = 0; g_ < 4; ++g_)                                           \
        tot[g_] += *(const floatx4*)&red[w2_][slot_ + g_][lane * 4];           \
    }                                                                          \
  }

// distributed flag barrier: flag[i] at FL[i*8] (32B stride). One writer per
// flag (atomic store, no RMW chain); wave-0's 64 lanes poll 64 flags in
// parallel (each lane a distinct dword) and combine with __all.
#define POLL1(FLA, TGTA)                                                       \
  if (wv == 0) {                                                               \
    int spins_ = 0;                                                            \
    for (;;) {                                                                 \
      unsigned va_ = ald((FLA) + lane * 8);                                    \
      if (__all((int)(va_ >= (TGTA)))) break;                                  \
      __builtin_amdgcn_s_sleep(1);                                             \
      if (++spins_ > (1 << 17)) break;                                         \
    }                                                                          \
  }
#define POLL2(FLA, TGTA, FLB, TGTB)                                            \
  if (wv == 0) {                                                               \
    int spins_ = 0;                                                            \
    for (;;) {                                                                 \
      unsigned va_ = ald((FLA) + lane * 8);                                    \
      unsigned vb_ = ald((FLB) + lane * 8);                                    \
      if (__all((int)((va_ >= (TGTA)) & (vb_ >= (TGTB))))) break;              \
      __builtin_amdgcn_s_sleep(1);                                             \
      if (++spins_ > (1 << 17)) break;                                         \
    }                                                                          \
  }

// ---------------- fused persistent 4-stage LSTM pipeline ----------------
// 256 WGs x 256 threads; group = blockIdx>>6:
//   0 = L0: h0 recurrence       (consumes G0 ring; Wh0 resident)
//   1 = P0: G0 = X[t] @ Wx0^T   (no upstream dep -> free-runs 8 ahead)
//   2 = P1: G1 = h0(t+1) @ Wx1^T
//   3 = L1: h1 recurrence       (consumes G1 ring; writes outputs)
// gemm_nt is GONE: P0 produces the layer-0 gate GEMM per step into an 8-deep
// ring, exactly mirroring the proven P1->G1->L1 machinery (round-5 scattered
// dword agent atomics; rounds 6/7 taught: do not repack). Every group is a
// K=1024 pass with its 128-VGPR weight slice register-resident.
// Flags (stride-8 dwords): fl0 @0 (L0/h0), fl1 @512 (L1/h1), fl2 @1024
// (P1/G1), fl3 @1536 (P0/G0). Store-only writers; 64-lane parallel polls.
// Gating: L0(t): fl0>=t & fl3>=t+1. P0(t): fl0>=t-7 (ring free). P1(t):
// fl0>=t+1 & fl1>=t-7. L1(t): fl2>=t+1 & fl1>=t.
__global__ __launch_bounds__(256, 1) void lstm_fused(
    const u16* __restrict__ Wh0b,   // [4096][1024] bf16
    const u16* __restrict__ Wx0b,   // [4096][1024] bf16
    const u16* __restrict__ Wx1b,   // [4096][1024] bf16
    const u16* __restrict__ Wh1b,   // [4096][1024] bf16
    const u16* __restrict__ Xb,     // [16384][1024] bf16 row-major
    const float* __restrict__ bias, // [2][4096]
    unsigned* H0u,                  // u32 blocked, 257 rows
    unsigned* H1u,
    unsigned* G0u,                  // ring: 8 x 131072 u32
    unsigned* G1u,                  // ring: 8 x 131072 u32
    unsigned* FL,
    float* __restrict__ outp,       // [256*64*1024] fp32 (layer-1 output)
    float* __restrict__ hf,         // [2*64*1024] fp32
    float* __restrict__ cf) {       // [2*64*1024] fp32
  __shared__ float red[4][12][256];
  const int tid = threadIdx.x;
  const int wv = tid >> 6;
  const int lane = tid & 63;
  const int q = lane >> 4;
  const int n16 = lane & 15;
  const int gid = blockIdx.x >> 6;
  const int jb = blockIdx.x & 63;
  const int jg = (jb << 4) + n16;
  const int kq0 = wv << 8;
  unsigned* fl0 = FL;
  unsigned* fl1 = FL + 512;
  unsigned* fl2 = FL + 1024;
  unsigned* fl3 = FL + 1536;
  const floatx4 vzero = {0.f, 0.f, 0.f, 0.f};

  if (gid == 0) {
    // ================= L0: layer-0 recurrence =================
    short8 wf[4][8];
#pragma unroll
    for (int g = 0; g < 4; ++g)
#pragma unroll
      for (int c = 0; c < 8; ++c)
        wf[g][c] = *(const short8*)(Wh0b + (size_t)(g * 1024 + jg) * 1024 + kq0 + c * 32 + q * 8);
#pragma unroll
    for (int g = 0; g < 4; ++g)
#pragma unroll
      for (int c = 0; c < 8; ++c) asm volatile("" : "+v"(wf[g][c]));

    float bs[4];
#pragma unroll
    for (int g = 0; g < 4; ++g) bs[g] = bias[g * 1024 + jg];
    float cst[4] = {0.f, 0.f, 0.f, 0.f};

    for (int t = 0; t < NSTEP; ++t) {
      POLL2(fl0, (unsigned)t, fl3, (unsigned)(t + 1));
      __syncthreads();

      // G0 fragment: scattered dword atomic loads (proven L1 pattern); these
      // issue before the GEMM fragment batch and share its MALL exposure.
      const unsigned* g0i = G0u + (size_t)(t & 7) * 131072 + jb * 2048;
      float gf[4][4];
#pragma unroll
      for (int g = 0; g < 4; ++g)
#pragma unroll
        for (int r = 0; r < 4; ++r) {
          int b = wv * 16 + q * 4 + r;
          unsigned dw = ald(g0i + g * 512 + b * 8 + (n16 >> 1));
          gf[g][r] = b2f((u16)(dw >> (16 * (n16 & 1))));
        }

      floatx4 acc[4][4];
#pragma unroll
      for (int m = 0; m < 4; ++m)
#pragma unroll
        for (int g = 0; g < 4; ++g) acc[m][g] = vzero;
      GEMM_Q(H0u + (size_t)t * 32768, wf);

      floatx4 tot[4];
      REDUCE_TOT();

      unsigned* hnext = H0u + (size_t)(t + 1) * 32768 + jb * 512;
      float hsv[4];
#pragma unroll
      for (int r = 0; r < 4; ++r) {
        float pi = tot[0][r] + gf[0][r] + bs[0];
        float pf = tot[1][r] + gf[1][r] + bs[1];
        float po = tot[2][r] + gf[2][r] + bs[2];
        float pc = tot[3][r] + gf[3][r] + bs[3];
        float cn = sigf(pf) * cst[r] + sigf(pi) * tanhf_fast(pc);
        float h = sigf(po) * tanhf_fast(cn);
        cst[r] = cn;
        hsv[r] = h;
        int brow = wv * 16 + q * 4 + r;
        unsigned hv = f2b_rne(h);
        unsigned pv = (unsigned)__shfl_xor((int)hv, 1);
        if (!(n16 & 1)) ast(hnext + brow * 8 + (n16 >> 1), hv | (pv << 16));
      }

      __syncthreads();  // drain h atomic stores (compiler vmcnt(0) at barrier)
      if (tid == 0) ast(fl0 + jb * 8, (unsigned)(t + 1));

      if (t == NSTEP - 1) {
#pragma unroll
        for (int r = 0; r < 4; ++r) {
          int brow = wv * 16 + q * 4 + r;
          hf[brow * 1024 + jg] = hsv[r];
          cf[brow * 1024 + jg] = cst[r];
        }
      }
    }
  } else if (gid == 1) {
    // ================= P0: G0 producer (X[t] @ Wx0^T) =================
    short8 wf[4][8];
#pragma unroll
    for (int g = 0; g < 4; ++g)
#pragma unroll
      for (int c = 0; c < 8; ++c)
        wf[g][c] = *(const short8*)(Wx0b + (size_t)(g * 1024 + jg) * 1024 + kq0 + c * 32 + q * 8);
#pragma unroll
    for (int g = 0; g < 4; ++g)
#pragma unroll
      for (int c = 0; c < 8; ++c) asm volatile("" : "+v"(wf[g][c]));

    for (int t = 0; t < NSTEP; ++t) {
      unsigned tgtb = (t >= 8) ? (unsigned)(t - 7) : 0u;  // ring slot free
      POLL1(fl0, tgtb);
      __syncthreads();

      floatx4 acc[4][4];
#pragma unroll
      for (int m = 0; m < 4; ++m)
#pragma unroll
        for (int g = 0; g < 4; ++g) acc[m][g] = vzero;
      GEMM_QX(Xb + (size_t)t * 65536, wf);

      floatx4 tot[4];
      REDUCE_TOT();

      // store G0[t] slice (round-5 scattered-dword pattern — frozen)
      unsigned* g0o = G0u + (size_t)(t & 7) * 131072 + jb * 2048;
#pragma unroll
      for (int r = 0; r < 4; ++r) {
        int b = wv * 16 + q * 4 + r;
#pragma unroll
        for (int g = 0; g < 4; ++g) {
          unsigned v = f2b_rne(tot[g][r]);
          unsigned pv = (unsigned)__shfl_xor((int)v, 1);
          if (!(n16 & 1)) ast(g0o + g * 512 + b * 8 + (n16 >> 1), v | (pv << 16));
        }
      }

      __syncthreads();  // drain G0 stores
      if (tid == 0) ast(fl3 + jb * 8, (unsigned)(t + 1));
    }
  } else if (gid == 2) {
    // ================= P1: G1 producer (h0(t+1) @ Wx1^T) =================
    short8 wf[4][8];
#pragma unroll
    for (int g = 0; g < 4; ++g)
#pragma unroll
      for (int c = 0; c < 8; ++c)
        wf[g][c] = *(const short8*)(Wx1b + (size_t)(g * 1024 + jg) * 1024 + kq0 + c * 32 + q * 8);
#pragma unroll
    for (int g = 0; g < 4; ++g)
#pragma unroll
      for (int c = 0; c < 8; ++c) asm volatile("" : "+v"(wf[g][c]));

    for (int t = 0; t < NSTEP; ++t) {
      unsigned tgtb = (t >= 8) ? (unsigned)(t - 7) : 0u;  // ring slot free
      POLL2(fl0, (unsigned)(t + 1), fl1, tgtb);
      __syncthreads();

      floatx4 acc[4][4];
#pragma unroll
      for (int m = 0; m < 4; ++m)
#pragma unroll
        for (int g = 0; g < 4; ++g) acc[m][g] = vzero;
      GEMM_Q(H0u + (size_t)(t + 1) * 32768, wf);

      floatx4 tot[4];
      REDUCE_TOT();

      unsigned* g1o = G1u + (size_t)(t & 7) * 131072 + jb * 2048;
#pragma unroll
      for (int r = 0; r < 4; ++r) {
        int b = wv * 16 + q * 4 + r;
#pragma unroll
        for (int g = 0; g < 4; ++g) {
          unsigned v = f2b_rne(tot[g][r]);
          unsigned pv = (unsigned)__shfl_xor((int)v, 1);
          if (!(n16 & 1)) ast(g1o + g * 512 + b * 8 + (n16 >> 1), v | (pv << 16));
        }
      }

      __syncthreads();  // drain G1 stores
      if (tid == 0) ast(fl2 + jb * 8, (unsigned)(t + 1));
    }
  } else {
    // ================= L1: layer-1 recurrence =================
    short8 wf[4][8];
#pragma unroll
    for (int g = 0; g < 4; ++g)
#pragma unroll
      for (int c = 0; c < 8; ++c)
        wf[g][c] = *(const short8*)(Wh1b + (size_t)(g * 1024 + jg) * 1024 + kq0 + c * 32 + q * 8);
#pragma unroll
    for (int g = 0; g < 4; ++g)
#pragma unroll
      for (int c = 0; c < 8; ++c) asm volatile("" : "+v"(wf[g][c]));

    float bs[4];
#pragma unroll
    for (int g = 0; g < 4; ++g) bs[g] = bias[4096 + g * 1024 + jg];
    float cst[4] = {0.f, 0.f, 0.f, 0.f};

    for (int t = 0; t < NSTEP; ++t) {
      POLL2(fl2, (unsigned)(t + 1), fl1, (unsigned)t);
      __syncthreads();

      // G1 fragment: scattered dword atomic loads (round-5 verified path)
      const unsigned* g1i = G1u + (size_t)(t & 7) * 131072 + jb * 2048;
      float gf[4][4];
#pragma unroll
      for (int g = 0; g < 4; ++g)
#pragma unroll
        for (int r = 0; r < 4; ++r) {
          int b = wv * 16 + q * 4 + r;
          unsigned dw = ald(g1i + g * 512 + b * 8 + (n16 >> 1));
          gf[g][r] = b2f((u16)(dw >> (16 * (n16 & 1))));
        }

      floatx4 acc[4][4];
#pragma unroll
      for (int m = 0; m < 4; ++m)
#pragma unroll
        for (int g = 0; g < 4; ++g) acc[m][g] = vzero;
      GEMM_Q(H1u + (size_t)t * 32768, wf);

      floatx4 tot[4];
      REDUCE_TOT();

      unsigned* hnext = H1u + (size_t)(t + 1) * 32768 + jb * 512;
      float hsv[4];
#pragma unroll
      for (int r = 0; r < 4; ++r) {
        float pi = tot[0][r] + gf[0][r] + bs[0];
        float pf = tot[1][r] + gf[1][r] + bs[1];
        float po = tot[2][r] + gf[2][r] + bs[2];
        float pc = tot[3][r] + gf[3][r] + bs[3];
        float cn = sigf(pf) * cst[r] + sigf(pi) * tanhf_fast(pc);
        float h = sigf(po) * tanhf_fast(cn);
        cst[r] = cn;
        hsv[r] = h;
        int brow = wv * 16 + q * 4 + r;
        unsigned hv = f2b_rne(h);
        unsigned pv = (unsigned)__shfl_xor((int)hv, 1);
        if (!(n16 & 1)) ast(hnext + brow * 8 + (n16 >> 1), hv | (pv << 16));
      }

      __syncthreads();  // drain h stores
      if (tid == 0) ast(fl1 + jb * 8, (unsigned)(t + 1));

      // tail: outputs (off critical path)
#pragma unroll
      for (int r = 0; r < 4; ++r) {
        int brow = wv * 16 + q * 4 + r;
        outp[((size_t)t * 64 + brow) * 1024 + jg] = hsv[r];
      }
      if (t == NSTEP - 1) {
#pragma unroll
        for (int r = 0; r < 4; ++r) {
          int brow = wv * 16 + q * 4 + r;
          hf[65536 + brow * 1024 + jg] = hsv[r];
          cf[65536 + brow * 1024 + jg] = cst[r];
        }
      }
    }
  }
}

// ---------------- launch ----------------
extern "C" void kernel_launch(void* const* d_in, const int* in_sizes, int n_in,
                              void* d_out, int out_size, void* d_ws, size_t ws_size,
                              hipStream_t stream) {
  const float* X  = (const float*)d_in[0];   // [256][64][1024]
  const float* Wx = (const float*)d_in[1];   // [2][4096][1024]
  const float* Wh = (const float*)d_in[2];   // [2][4096][1024]
  const float* b  = (const float*)d_in[3];   // [2][4096]
  float* out = (float*)d_out;

  char* ws = (char*)d_ws;
  u16* Xbf  = (u16*)(ws);                         // 33,554,432 B (ALIVE: P0 reads it)
  u16* Wxbf = (u16*)(ws + 33554432);              // 16,777,216 B
  u16* Whbf = (u16*)(ws + 50331648);              // 16,777,216 B
  unsigned* H0 = (unsigned*)(ws + 67108864);      // 33,685,504 B (257*131072)
  unsigned* H1 = (unsigned*)(ws + 100794368);     // 33,685,504 B
  unsigned* G0 = (unsigned*)(ws + 134479872);     // ring 8 x 512 KB = 4 MB
  unsigned* G1 = (unsigned*)(ws + 138674176);     // ring 8 x 512 KB = 4 MB
  unsigned* FL = (unsigned*)(ws + 142868480);     // flags, 8 KB

  float* out_seq = out;                // 16,777,216 floats
  float* Hf = out + 16777216;          // 131,072 floats
  float* Cf = out + 16777216 + 131072; // 131,072 floats

  init_kernel<<<128, 256, 0, stream>>>(H0, H1);
  init2_kernel<<<8, 256, 0, stream>>>(FL);
  cast_kernel<<<2048, 256, 0, stream>>>(X, Xbf, 16777216 / 4);
  cast_kernel<<<2048, 256, 0, stream>>>(Wx, Wxbf, 8388608 / 4);
  cast_kernel<<<2048, 256, 0, stream>>>(Wh, Whbf, 8388608 / 4);

  // fused 4-stage pipeline: L0 | P0 (X@Wx0) | P1 (h0@Wx1) | L1
  lstm_fused<<<256, 256, 0, stream>>>(Whbf, Wxbf, Wxbf + 4194304, Whbf + 4194304,
                                      Xbf, b, H0, H1, G0, G1, FL, out_seq, Hf, Cf);
}